// Round 2
// baseline (1154.714 us; speedup 1.0000x reference)
//
#include <hip/hip_runtime.h>
#include <hip/hip_bf16.h>
#include <cstdint>
#include <cstddef>

#define NN   100000
#define NE   1600000
#define HID  256
#define OUTC 40

typedef __attribute__((ext_vector_type(8))) short bf16x8;
typedef __attribute__((ext_vector_type(4))) float f32x4;

static __device__ __forceinline__ ushort f2bf(float f) {
    __hip_bfloat16 h = __float2bfloat16(f);
    return *reinterpret_cast<ushort*>(&h);
}
static __device__ __forceinline__ float bflo(unsigned u) { return __uint_as_float(u << 16); }
static __device__ __forceinline__ float bfhi(unsigned u) { return __uint_as_float(u & 0xffff0000u); }

// ---------------- CSR build ----------------
__global__ void k_count(const int* __restrict__ dst, int* __restrict__ cnt) {
    int i = blockIdx.x * blockDim.x + threadIdx.x;
    if (i < NE) atomicAdd(&cnt[dst[i]], 1);
}

__global__ void k_blocksum(const int* __restrict__ cnt, int* __restrict__ bsum) {
    __shared__ int s[256];
    int t = threadIdx.x;
    int n = blockIdx.x * 256 + t;
    s[t] = (n < NN) ? cnt[n] : 0;
    __syncthreads();
    for (int off = 128; off; off >>= 1) {
        if (t < off) s[t] += s[t + off];
        __syncthreads();
    }
    if (t == 0) bsum[blockIdx.x] = s[0];
}

__global__ void k_scanblock(const int* __restrict__ bsum, int* __restrict__ boff, int nb) {
    __shared__ int s[512];
    int t = threadIdx.x;
    int v = (t < nb) ? bsum[t] : 0;
    s[t] = v;
    __syncthreads();
    for (int off = 1; off < 512; off <<= 1) {
        int u = (t >= off) ? s[t - off] : 0;
        __syncthreads();
        s[t] += u;
        __syncthreads();
    }
    if (t < nb) boff[t] = s[t] - v;
}

__global__ void k_rowptr(const int* __restrict__ cnt, const int* __restrict__ boff,
                         int* __restrict__ rowptr, int* __restrict__ fillp,
                         float* __restrict__ invd) {
    __shared__ int s[256];
    int t = threadIdx.x;
    int n = blockIdx.x * 256 + t;
    int c = (n < NN) ? cnt[n] : 0;
    s[t] = c;
    __syncthreads();
    for (int off = 1; off < 256; off <<= 1) {
        int u = (t >= off) ? s[t - off] : 0;
        __syncthreads();
        s[t] += u;
        __syncthreads();
    }
    if (n < NN) {
        int excl = boff[blockIdx.x] + s[t] - c;
        rowptr[n] = excl;
        fillp[n]  = excl;
        invd[n]   = 1.0f / (float)(c > 1 ? c : 1);
    }
    if (n == 0) rowptr[NN] = NE;
}

__global__ void k_fill(const int* __restrict__ src, const int* __restrict__ dst,
                       int* __restrict__ fillp, int* __restrict__ colidx) {
    int i = blockIdx.x * blockDim.x + threadIdx.x;
    if (i < NE) {
        int p = atomicAdd(&fillp[dst[i]], 1);
        colidx[p] = src[i];
    }
}

// ---------------- fp32 -> bf16 weight conversion ----------------
__global__ void k_cvt(const float* __restrict__ srcp, ushort* __restrict__ dstp, int n) {
    int i = blockIdx.x * blockDim.x + threadIdx.x;
    if (i < n) dstp[i] = f2bf(srcp[i]);
}

// ---------------- fused layer: CSR mean-aggregate (LDS) + dual bf16 MFMA GEMM ----------------
template<typename InT>
static __device__ __forceinline__ void addrow(float* acc, const InT* p) {
    if constexpr (sizeof(InT) == 4) {
        float4 a0 = ((const float4*)p)[0], a1 = ((const float4*)p)[1];
        acc[0] += a0.x; acc[1] += a0.y; acc[2] += a0.z; acc[3] += a0.w;
        acc[4] += a1.x; acc[5] += a1.y; acc[6] += a1.z; acc[7] += a1.w;
    } else {
        uint4 u0 = ((const uint4*)p)[0], u1 = ((const uint4*)p)[1];
        acc[0]  += bflo(u0.x); acc[1]  += bfhi(u0.x);
        acc[2]  += bflo(u0.y); acc[3]  += bfhi(u0.y);
        acc[4]  += bflo(u0.z); acc[5]  += bfhi(u0.z);
        acc[6]  += bflo(u0.w); acc[7]  += bfhi(u0.w);
        acc[8]  += bflo(u1.x); acc[9]  += bfhi(u1.x);
        acc[10] += bflo(u1.y); acc[11] += bfhi(u1.y);
        acc[12] += bflo(u1.z); acc[13] += bfhi(u1.z);
        acc[14] += bflo(u1.w); acc[15] += bfhi(u1.w);
    }
}

template<int D, typename InT, int OC, bool RELU, typename OutT>
__global__ __launch_bounds__(256, 4) void k_layer(
    const InT* __restrict__ hin,      // [NN][D]
    const ushort* __restrict__ Wl,    // [OC][D] bf16
    const ushort* __restrict__ Wr,    // [OC][D] bf16
    const float* __restrict__ bias,   // [OC]
    const float* __restrict__ invd,
    const int* __restrict__ rowptr,
    const int* __restrict__ colidx,
    OutT* __restrict__ hout)          // [NN][OC]
{
    __shared__ ushort aggS[64 * D];   // bf16, 16B-granule XOR-swizzled rows
    char* aggSb = (char*)aggS;
    const int t  = threadIdx.x;
    const int r0 = blockIdx.x * 64;
    constexpr int FPL = (sizeof(InT) == 4) ? 8 : 16;  // feats per lane (32B)

    // ---- phase 1: mean-aggregate 64 rows into LDS (quarter-wave per row) ----
    {
        const int qw = t >> 4, ql = t & 15;
        for (int rr = qw; rr < 64; rr += 16) {
            const int r = r0 + rr;
            float acc[FPL];
            #pragma unroll
            for (int j = 0; j < FPL; ++j) acc[j] = 0.f;
            if (r < NN) {
                const int beg = rowptr[r], end = rowptr[r + 1];
                const float sc = invd[r];
                int e = beg;
                for (; e + 1 < end; e += 2) {
                    int s0 = colidx[e], s1 = colidx[e + 1];
                    addrow<InT>(acc, hin + (size_t)s0 * D + ql * FPL);
                    addrow<InT>(acc, hin + (size_t)s1 * D + ql * FPL);
                }
                if (e < end) {
                    int s0 = colidx[e];
                    addrow<InT>(acc, hin + (size_t)s0 * D + ql * FPL);
                }
                #pragma unroll
                for (int j = 0; j < FPL; ++j) acc[j] *= sc;
            }
            #pragma unroll
            for (int gg = 0; gg < FPL / 8; ++gg) {
                unsigned q0 = (unsigned)f2bf(acc[gg*8+0]) | ((unsigned)f2bf(acc[gg*8+1]) << 16);
                unsigned q1 = (unsigned)f2bf(acc[gg*8+2]) | ((unsigned)f2bf(acc[gg*8+3]) << 16);
                unsigned q2 = (unsigned)f2bf(acc[gg*8+4]) | ((unsigned)f2bf(acc[gg*8+5]) << 16);
                unsigned q3 = (unsigned)f2bf(acc[gg*8+6]) | ((unsigned)f2bf(acc[gg*8+7]) << 16);
                int g  = ql * (FPL / 8) + gg;
                int gs = g ^ (rr & 7);
                *(uint4*)(aggSb + (size_t)rr * (D * 2) + (gs << 4)) = make_uint4(q0, q1, q2, q3);
            }
        }
    }
    __syncthreads();

    // ---- phase 2: per-wave 16-row MFMA GEMM over OC in 16-col chunks ----
    const int w  = t >> 6, l = t & 63;
    const int lm = l & 15, lk = l >> 4;
    const int rr = w * 16 + lm;          // A-row within block
    const int rg = r0 + rr;
    constexpr int NCH = (OC + 15) / 16;

    for (int cc = 0; cc < NCH; ++cc) {
        const int c = cc * 16 + lm;
        f32x4 acc = {0.f, 0.f, 0.f, 0.f};
        #pragma unroll
        for (int kk = 0; kk < D / 32; ++kk) {
            const int g  = kk * 4 + lk;
            const int gs = g ^ (rr & 7);
            bf16x8 a_agg = *(const bf16x8*)(aggSb + (size_t)rr * (D * 2) + (gs << 4));
            bf16x8 a_x;
            if (rg < NN) {
                if constexpr (sizeof(InT) == 4) {
                    const float* p = (const float*)hin + (size_t)rg * D + kk * 32 + lk * 8;
                    float4 f0 = ((const float4*)p)[0], f1 = ((const float4*)p)[1];
                    a_x[0] = (short)f2bf(f0.x); a_x[1] = (short)f2bf(f0.y);
                    a_x[2] = (short)f2bf(f0.z); a_x[3] = (short)f2bf(f0.w);
                    a_x[4] = (short)f2bf(f1.x); a_x[5] = (short)f2bf(f1.y);
                    a_x[6] = (short)f2bf(f1.z); a_x[7] = (short)f2bf(f1.w);
                } else {
                    a_x = *(const bf16x8*)((const ushort*)hin + (size_t)rg * D + kk * 32 + lk * 8);
                }
            } else {
                a_x = (bf16x8)(short)0;
            }
            bf16x8 bl, br;
            if (c < OC) {
                bl = *(const bf16x8*)(Wl + (size_t)c * D + kk * 32 + lk * 8);
                br = *(const bf16x8*)(Wr + (size_t)c * D + kk * 32 + lk * 8);
            } else {
                bl = (bf16x8)(short)0; br = bl;
            }
            acc = __builtin_amdgcn_mfma_f32_16x16x32_bf16(a_agg, bl, acc, 0, 0, 0);
            acc = __builtin_amdgcn_mfma_f32_16x16x32_bf16(a_x,   br, acc, 0, 0, 0);
        }
        const float bv = (c < OC) ? bias[c] : 0.f;
        #pragma unroll
        for (int i = 0; i < 4; ++i) {
            const int orow = r0 + w * 16 + lk * 4 + i;
            if (orow < NN && c < OC) {
                float v = acc[i] + bv;
                if (RELU) v = fmaxf(v, 0.f);
                if constexpr (sizeof(OutT) == 2)
                    *(ushort*)&hout[(size_t)orow * OC + c] = f2bf(v);
                else
                    hout[(size_t)orow * OC + c] = *(OutT*)&v;
            }
        }
    }
}

// ---------------- row-wise log_softmax over OUTC=40, one wave per row ----------------
__global__ void k_logsoftmax(float* __restrict__ out, int n) {
    int wid  = (blockIdx.x * blockDim.x + threadIdx.x) >> 6;
    int lane = threadIdx.x & 63;
    if (wid >= n) return;
    float v = (lane < OUTC) ? out[(size_t)wid * OUTC + lane] : -INFINITY;
    float m = v;
    #pragma unroll
    for (int off = 32; off; off >>= 1) m = fmaxf(m, __shfl_xor(m, off));
    float ex = (lane < OUTC) ? __expf(v - m) : 0.0f;
    float s = ex;
    #pragma unroll
    for (int off = 32; off; off >>= 1) s += __shfl_xor(s, off);
    float ls = __logf(s);
    if (lane < OUTC) out[(size_t)wid * OUTC + lane] = v - m - ls;
}

extern "C" void kernel_launch(void* const* d_in, const int* in_sizes, int n_in,
                              void* d_out, int out_size, void* d_ws, size_t ws_size,
                              hipStream_t stream) {
    const float* x   = (const float*)d_in[0];
    const int*   ei  = (const int*)d_in[1];
    const int*   src = ei;
    const int*   dst = ei + NE;
    const float* Wl0 = (const float*)d_in[2];
    const float* Wr0 = (const float*)d_in[3];
    const float* b0  = (const float*)d_in[4];
    const float* Wl1 = (const float*)d_in[5];
    const float* Wr1 = (const float*)d_in[6];
    const float* b1  = (const float*)d_in[7];
    const float* Wlo = (const float*)d_in[8];
    const float* Wro = (const float*)d_in[9];
    const float* bo  = (const float*)d_in[10];
    float* out = (float*)d_out;

    char* ws = (char*)d_ws;
    const size_t MB = 1 << 20;
    float*  invd   = (float*)(ws + 0);
    int*    rowptr = (int*)(ws + MB / 2);
    int*    cnt    = (int*)(ws + MB);
    int*    fillp  = (int*)(ws + MB + MB / 2);
    int*    bsum   = (int*)(ws + 2 * MB);
    int*    boff   = (int*)(ws + 2 * MB + MB / 4);
    ushort* Wb     = (ushort*)(ws + 2 * MB + MB / 2);
    int*    colidx = (int*)(ws + 3 * MB);
    ushort* h0     = (ushort*)(ws + 10 * MB);          // [NN][256] bf16 = 51.2MB
    ushort* h1     = (ushort*)(ws + 64 * MB);          // [NN][256] bf16 = 51.2MB

    ushort* wl0 = Wb;
    ushort* wr0 = Wb + 32768;
    ushort* wl1 = Wb + 65536;
    ushort* wr1 = Wb + 131072;
    ushort* wlo = Wb + 196608;
    ushort* wro = Wb + 206848;

    // CSR build
    hipMemsetAsync(cnt, 0, NN * sizeof(int), stream);
    k_count<<<(NE + 255) / 256, 256, 0, stream>>>(dst, cnt);
    const int NB = (NN + 255) / 256;  // 391
    k_blocksum<<<NB, 256, 0, stream>>>(cnt, bsum);
    k_scanblock<<<1, 512, 0, stream>>>(bsum, boff, NB);
    k_rowptr<<<NB, 256, 0, stream>>>(cnt, boff, rowptr, fillp, invd);
    k_fill<<<(NE + 255) / 256, 256, 0, stream>>>(src, dst, fillp, colidx);

    // weights -> bf16
    k_cvt<<<(32768 + 255) / 256, 256, 0, stream>>>(Wl0, wl0, 32768);
    k_cvt<<<(32768 + 255) / 256, 256, 0, stream>>>(Wr0, wr0, 32768);
    k_cvt<<<(65536 + 255) / 256, 256, 0, stream>>>(Wl1, wl1, 65536);
    k_cvt<<<(65536 + 255) / 256, 256, 0, stream>>>(Wr1, wr1, 65536);
    k_cvt<<<(10240 + 255) / 256, 256, 0, stream>>>(Wlo, wlo, 10240);
    k_cvt<<<(10240 + 255) / 256, 256, 0, stream>>>(Wro, wro, 10240);

    const int GB = (NN + 63) / 64;  // 1563
    // layer 0: x fp32 [N,128] -> h0 bf16 [N,256]
    k_layer<128, float, HID, true, ushort><<<GB, 256, 0, stream>>>(
        x, wl0, wr0, b0, invd, rowptr, colidx, h0);
    // layer 1: h0 -> h1
    k_layer<256, ushort, HID, true, ushort><<<GB, 256, 0, stream>>>(
        h0, wl1, wr1, b1, invd, rowptr, colidx, h1);
    // layer 2: h1 -> out fp32 [N,40]
    k_layer<256, ushort, OUTC, false, float><<<GB, 256, 0, stream>>>(
        h1, wlo, wro, bo, invd, rowptr, colidx, out);

    k_logsoftmax<<<(NN + 3) / 4, 256, 0, stream>>>(out, NN);
}

// Round 3
// 1095.844 us; speedup vs baseline: 1.0537x; 1.0537x over previous
//
#include <hip/hip_runtime.h>
#include <hip/hip_bf16.h>
#include <cstdint>
#include <cstddef>

#define NN   100000
#define NE   1600000
#define HID  256
#define OUTC 40

typedef __attribute__((ext_vector_type(8))) short bf16x8;
typedef __attribute__((ext_vector_type(4))) float f32x4;

static __device__ __forceinline__ ushort f2bf(float f) {
    __hip_bfloat16 h = __float2bfloat16(f);
    return *reinterpret_cast<ushort*>(&h);
}
static __device__ __forceinline__ float bflo(unsigned u) { return __uint_as_float(u << 16); }
static __device__ __forceinline__ float bfhi(unsigned u) { return __uint_as_float(u & 0xffff0000u); }

// ---------------- CSR build ----------------
__global__ void k_count(const int* __restrict__ dst, int* __restrict__ cnt) {
    int i = blockIdx.x * blockDim.x + threadIdx.x;
    if (i < NE) atomicAdd(&cnt[dst[i]], 1);
}

__global__ void k_blocksum(const int* __restrict__ cnt, int* __restrict__ bsum) {
    __shared__ int s[256];
    int t = threadIdx.x;
    int n = blockIdx.x * 256 + t;
    s[t] = (n < NN) ? cnt[n] : 0;
    __syncthreads();
    for (int off = 128; off; off >>= 1) {
        if (t < off) s[t] += s[t + off];
        __syncthreads();
    }
    if (t == 0) bsum[blockIdx.x] = s[0];
}

__global__ void k_scanblock(const int* __restrict__ bsum, int* __restrict__ boff, int nb) {
    __shared__ int s[512];
    int t = threadIdx.x;
    int v = (t < nb) ? bsum[t] : 0;
    s[t] = v;
    __syncthreads();
    for (int off = 1; off < 512; off <<= 1) {
        int u = (t >= off) ? s[t - off] : 0;
        __syncthreads();
        s[t] += u;
        __syncthreads();
    }
    if (t < nb) boff[t] = s[t] - v;
}

__global__ void k_rowptr(const int* __restrict__ cnt, const int* __restrict__ boff,
                         int* __restrict__ rowptr, int* __restrict__ fillp,
                         float* __restrict__ invd) {
    __shared__ int s[256];
    int t = threadIdx.x;
    int n = blockIdx.x * 256 + t;
    int c = (n < NN) ? cnt[n] : 0;
    s[t] = c;
    __syncthreads();
    for (int off = 1; off < 256; off <<= 1) {
        int u = (t >= off) ? s[t - off] : 0;
        __syncthreads();
        s[t] += u;
        __syncthreads();
    }
    if (n < NN) {
        int excl = boff[blockIdx.x] + s[t] - c;
        rowptr[n] = excl;
        fillp[n]  = excl;
        invd[n]   = 1.0f / (float)(c > 1 ? c : 1);
    }
    if (n == 0) rowptr[NN] = NE;
}

__global__ void k_fill(const int* __restrict__ src, const int* __restrict__ dst,
                       int* __restrict__ fillp, int* __restrict__ colidx) {
    int i = blockIdx.x * blockDim.x + threadIdx.x;
    if (i < NE) {
        int p = atomicAdd(&fillp[dst[i]], 1);
        colidx[p] = src[i];
    }
}

// ---------------- fp32 -> bf16 conversion, 4 elements/thread ----------------
__global__ void k_cvt4(const float* __restrict__ srcp, ushort* __restrict__ dstp, int n4) {
    int i = blockIdx.x * blockDim.x + threadIdx.x;
    if (i < n4) {
        float4 f = ((const float4*)srcp)[i];
        uint2 o;
        o.x = (unsigned)f2bf(f.x) | ((unsigned)f2bf(f.y) << 16);
        o.y = (unsigned)f2bf(f.z) | ((unsigned)f2bf(f.w) << 16);
        ((uint2*)dstp)[i] = o;
    }
}

// ---------------- fused layer: CSR mean-aggregate (LDS) + dual bf16 MFMA GEMM ----------------
// hin is [NN][D] bf16. Gather phase: quarter-wave (16 lanes) per dst row, each lane
// owns FPL=D/16 features (16B or 32B). Edge loop unrolled EU-wide with loads batched
// ahead of accumulation for memory-level parallelism (8 uint4 in flight per lane).
template<int D, int OC, bool RELU, typename OutT>
__global__ __launch_bounds__(256, 4) void k_layer(
    const ushort* __restrict__ hin,   // [NN][D] bf16
    const ushort* __restrict__ Wl,    // [OC][D] bf16
    const ushort* __restrict__ Wr,    // [OC][D] bf16
    const float* __restrict__ bias,   // [OC]
    const float* __restrict__ invd,
    const int* __restrict__ rowptr,
    const int* __restrict__ colidx,
    OutT* __restrict__ hout)          // [NN][OC]
{
    __shared__ ushort aggS[64 * D];   // bf16, 16B-granule XOR-swizzled rows
    char* aggSb = (char*)aggS;
    const int t  = threadIdx.x;
    const int r0 = blockIdx.x * 64;
    constexpr int FPL = D / 16;        // features per lane: 8 (D=128) or 16 (D=256)
    constexpr int NU4 = FPL / 8;       // uint4 loads per edge per lane: 1 or 2
    constexpr int EU  = 8 / NU4;       // edges per unrolled iter -> 8 uint4 in flight

    // ---- phase 1: mean-aggregate 64 rows into LDS ----
    {
        const int qw = t >> 4, ql = t & 15;
        for (int rr = qw; rr < 64; rr += 16) {
            const int r = r0 + rr;
            float acc[FPL];
            #pragma unroll
            for (int j = 0; j < FPL; ++j) acc[j] = 0.f;
            if (r < NN) {
                const int beg = rowptr[r], end = rowptr[r + 1];
                const float sc = invd[r];
                int e = beg;
                for (; e + (EU - 1) < end; e += EU) {
                    uint4 u[8];
                    #pragma unroll
                    for (int j = 0; j < EU; ++j) {
                        int s = colidx[e + j];
                        const uint4* p = (const uint4*)(hin + (size_t)s * D + ql * FPL);
                        u[j * NU4] = p[0];
                        if (NU4 == 2) u[j * NU4 + 1] = p[1];
                    }
                    #pragma unroll
                    for (int j = 0; j < EU; ++j) {
                        #pragma unroll
                        for (int q = 0; q < NU4; ++q) {
                            uint4 v = u[j * NU4 + q];
                            acc[q*8+0] += bflo(v.x); acc[q*8+1] += bfhi(v.x);
                            acc[q*8+2] += bflo(v.y); acc[q*8+3] += bfhi(v.y);
                            acc[q*8+4] += bflo(v.z); acc[q*8+5] += bfhi(v.z);
                            acc[q*8+6] += bflo(v.w); acc[q*8+7] += bfhi(v.w);
                        }
                    }
                }
                for (; e < end; ++e) {
                    int s = colidx[e];
                    const uint4* p = (const uint4*)(hin + (size_t)s * D + ql * FPL);
                    #pragma unroll
                    for (int q = 0; q < NU4; ++q) {
                        uint4 v = p[q];
                        acc[q*8+0] += bflo(v.x); acc[q*8+1] += bfhi(v.x);
                        acc[q*8+2] += bflo(v.y); acc[q*8+3] += bfhi(v.y);
                        acc[q*8+4] += bflo(v.z); acc[q*8+5] += bfhi(v.z);
                        acc[q*8+6] += bflo(v.w); acc[q*8+7] += bfhi(v.w);
                    }
                }
                #pragma unroll
                for (int j = 0; j < FPL; ++j) acc[j] *= sc;
            }
            #pragma unroll
            for (int gg = 0; gg < NU4; ++gg) {
                unsigned q0 = (unsigned)f2bf(acc[gg*8+0]) | ((unsigned)f2bf(acc[gg*8+1]) << 16);
                unsigned q1 = (unsigned)f2bf(acc[gg*8+2]) | ((unsigned)f2bf(acc[gg*8+3]) << 16);
                unsigned q2 = (unsigned)f2bf(acc[gg*8+4]) | ((unsigned)f2bf(acc[gg*8+5]) << 16);
                unsigned q3 = (unsigned)f2bf(acc[gg*8+6]) | ((unsigned)f2bf(acc[gg*8+7]) << 16);
                int g  = ql * NU4 + gg;
                int gs = g ^ (rr & 7);
                *(uint4*)(aggSb + (size_t)rr * (D * 2) + (gs << 4)) = make_uint4(q0, q1, q2, q3);
            }
        }
    }
    __syncthreads();

    // ---- phase 2: per-wave 16-row MFMA GEMM over OC in 16-col chunks ----
    const int w  = t >> 6, l = t & 63;
    const int lm = l & 15, lk = l >> 4;
    const int rr = w * 16 + lm;          // A-row within block
    const int rg = r0 + rr;
    constexpr int NCH = (OC + 15) / 16;

    for (int cc = 0; cc < NCH; ++cc) {
        const int c = cc * 16 + lm;
        f32x4 acc = {0.f, 0.f, 0.f, 0.f};
        #pragma unroll
        for (int kk = 0; kk < D / 32; ++kk) {
            const int g  = kk * 4 + lk;
            const int gs = g ^ (rr & 7);
            bf16x8 a_agg = *(const bf16x8*)(aggSb + (size_t)rr * (D * 2) + (gs << 4));
            bf16x8 a_x;
            if (rg < NN) {
                a_x = *(const bf16x8*)(hin + (size_t)rg * D + kk * 32 + lk * 8);
            } else {
                a_x = (bf16x8)(short)0;
            }
            bf16x8 bl, br;
            if (c < OC) {
                bl = *(const bf16x8*)(Wl + (size_t)c * D + kk * 32 + lk * 8);
                br = *(const bf16x8*)(Wr + (size_t)c * D + kk * 32 + lk * 8);
            } else {
                bl = (bf16x8)(short)0; br = bl;
            }
            acc = __builtin_amdgcn_mfma_f32_16x16x32_bf16(a_agg, bl, acc, 0, 0, 0);
            acc = __builtin_amdgcn_mfma_f32_16x16x32_bf16(a_x,   br, acc, 0, 0, 0);
        }
        const float bv = (c < OC) ? bias[c] : 0.f;
        #pragma unroll
        for (int i = 0; i < 4; ++i) {
            const int orow = r0 + w * 16 + lk * 4 + i;
            if (orow < NN && c < OC) {
                float v = acc[i] + bv;
                if (RELU) v = fmaxf(v, 0.f);
                if constexpr (sizeof(OutT) == 2)
                    *(ushort*)&hout[(size_t)orow * OC + c] = f2bf(v);
                else
                    hout[(size_t)orow * OC + c] = *(OutT*)&v;
            }
        }
    }
}

// ---------------- row-wise log_softmax over OUTC=40, one wave per row ----------------
__global__ void k_logsoftmax(float* __restrict__ out, int n) {
    int wid  = (blockIdx.x * blockDim.x + threadIdx.x) >> 6;
    int lane = threadIdx.x & 63;
    if (wid >= n) return;
    float v = (lane < OUTC) ? out[(size_t)wid * OUTC + lane] : -INFINITY;
    float m = v;
    #pragma unroll
    for (int off = 32; off; off >>= 1) m = fmaxf(m, __shfl_xor(m, off));
    float ex = (lane < OUTC) ? __expf(v - m) : 0.0f;
    float s = ex;
    #pragma unroll
    for (int off = 32; off; off >>= 1) s += __shfl_xor(s, off);
    float ls = __logf(s);
    if (lane < OUTC) out[(size_t)wid * OUTC + lane] = v - m - ls;
}

extern "C" void kernel_launch(void* const* d_in, const int* in_sizes, int n_in,
                              void* d_out, int out_size, void* d_ws, size_t ws_size,
                              hipStream_t stream) {
    const float* x   = (const float*)d_in[0];
    const int*   ei  = (const int*)d_in[1];
    const int*   src = ei;
    const int*   dst = ei + NE;
    const float* Wl0 = (const float*)d_in[2];
    const float* Wr0 = (const float*)d_in[3];
    const float* b0  = (const float*)d_in[4];
    const float* Wl1 = (const float*)d_in[5];
    const float* Wr1 = (const float*)d_in[6];
    const float* b1  = (const float*)d_in[7];
    const float* Wlo = (const float*)d_in[8];
    const float* Wro = (const float*)d_in[9];
    const float* bo  = (const float*)d_in[10];
    float* out = (float*)d_out;

    char* ws = (char*)d_ws;
    const size_t MB = 1 << 20;
    float*  invd   = (float*)(ws + 0);
    int*    rowptr = (int*)(ws + MB / 2);
    int*    cnt    = (int*)(ws + MB);
    int*    fillp  = (int*)(ws + MB + MB / 2);
    int*    bsum   = (int*)(ws + 2 * MB);
    int*    boff   = (int*)(ws + 2 * MB + MB / 4);
    ushort* Wb     = (ushort*)(ws + 2 * MB + MB / 2);
    int*    colidx = (int*)(ws + 3 * MB);
    ushort* h0     = (ushort*)(ws + 10 * MB);          // [NN][256] bf16 = 51.2MB
    ushort* h1     = (ushort*)(ws + 62 * MB);          // [NN][256] bf16 = 51.2MB
    ushort* xb     = (ushort*)(ws + 62 * MB);          // [NN][128] bf16 = 25.6MB (aliases h1;
                                                        //  xb dead before layer1 writes h1)

    ushort* wl0 = Wb;
    ushort* wr0 = Wb + 32768;
    ushort* wl1 = Wb + 65536;
    ushort* wr1 = Wb + 131072;
    ushort* wlo = Wb + 196608;
    ushort* wro = Wb + 206848;

    // CSR build
    hipMemsetAsync(cnt, 0, NN * sizeof(int), stream);
    k_count<<<(NE + 255) / 256, 256, 0, stream>>>(dst, cnt);
    const int NB = (NN + 255) / 256;  // 391
    k_blocksum<<<NB, 256, 0, stream>>>(cnt, bsum);
    k_scanblock<<<1, 512, 0, stream>>>(bsum, boff, NB);
    k_rowptr<<<NB, 256, 0, stream>>>(cnt, boff, rowptr, fillp, invd);
    k_fill<<<(NE + 255) / 256, 256, 0, stream>>>(src, dst, fillp, colidx);

    // weights + x -> bf16
    k_cvt4<<<(32768/4 + 255) / 256, 256, 0, stream>>>(Wl0, wl0, 32768/4);
    k_cvt4<<<(32768/4 + 255) / 256, 256, 0, stream>>>(Wr0, wr0, 32768/4);
    k_cvt4<<<(65536/4 + 255) / 256, 256, 0, stream>>>(Wl1, wl1, 65536/4);
    k_cvt4<<<(65536/4 + 255) / 256, 256, 0, stream>>>(Wr1, wr1, 65536/4);
    k_cvt4<<<(10240/4 + 255) / 256, 256, 0, stream>>>(Wlo, wlo, 10240/4);
    k_cvt4<<<(10240/4 + 255) / 256, 256, 0, stream>>>(Wro, wro, 10240/4);
    k_cvt4<<<(NN*128/4 + 255) / 256, 256, 0, stream>>>(x, xb, NN*128/4);

    const int GB = (NN + 63) / 64;  // 1563
    // layer 0: xb bf16 [N,128] -> h0 bf16 [N,256]
    k_layer<128, HID, true, ushort><<<GB, 256, 0, stream>>>(
        xb, wl0, wr0, b0, invd, rowptr, colidx, h0);
    // layer 1: h0 -> h1
    k_layer<256, HID, true, ushort><<<GB, 256, 0, stream>>>(
        h0, wl1, wr1, b1, invd, rowptr, colidx, h1);
    // layer 2: h1 -> out fp32 [N,40]
    k_layer<256, OUTC, false, float><<<GB, 256, 0, stream>>>(
        h1, wlo, wro, bo, invd, rowptr, colidx, out);

    k_logsoftmax<<<(NN + 3) / 4, 256, 0, stream>>>(out, NN);
}